// Round 10
// baseline (215.198 us; speedup 1.0000x reference)
//
#include <hip/hip_runtime.h>
#include <cstdint>

typedef unsigned short u16;
typedef __bf16 bf16x8 __attribute__((ext_vector_type(8)));
typedef float f32x4 __attribute__((ext_vector_type(4)));

#define M_DIM 8192
#define N_DIM 1024
#define I_DIM 1024
#define NDEG 8                    /* stored degrees d=1..8 */
#define K_DIM (I_DIM * NDEG)      /* 8192 */
#define BM 256
#define BN 128
#define BK 64
#define NT (K_DIM / BK)           /* 128 K-tiles */
#define A_TILE (BM * BK)          /* 16384 u16 = 32 KB */
#define B_TILE (BN * BK)          /* 8192  u16 = 16 KB */

__device__ __forceinline__ u16 f2bf(float f) {
    union { float f; uint32_t u; } v; v.f = f;
    return (u16)((v.u + 0x7FFFu + ((v.u >> 16) & 1u)) >> 16);
}

__device__ __forceinline__ void gload_lds16(const u16* g, u16* l) {
    auto lp = reinterpret_cast<__attribute__((address_space(3))) uint32_t*>(
        reinterpret_cast<uintptr_t>(l));
    __builtin_amdgcn_global_load_lds(reinterpret_cast<const uint32_t*>(g), lp, 16, 0, 0);
}

// ---------------------------------------------------------------------------
// Kernel 1: LDS-transposed transform.
//   Bt[o][i*8+d'] = (bf16) coeffs[i][o][1+d'],  bias[o] += sum_i coeffs[i][o][0]
// ---------------------------------------------------------------------------
__global__ __launch_bounds__(256) void aw_transform(
    const float* __restrict__ coeffs, u16* __restrict__ Bt, float* __restrict__ bias)
{
    __shared__ float lds[32][292];
    int bi = blockIdx.x >> 5, bo = blockIdx.x & 31;
    int i0 = bi * 32, o0 = bo * 32;
    int t = threadIdx.x;

    {
        int r = t >> 3, s = t & 7;
        const float4* src = (const float4*)(coeffs + ((size_t)(i0 + r) * N_DIM + o0) * 9);
#pragma unroll
        for (int j = 0; j < 9; ++j) {
            float4 v = src[s * 9 + j];
            *(float4*)&lds[r][(s * 9 + j) * 4] = v;
        }
    }
    __syncthreads();

    {
        int c = t >> 3, s2 = t & 7;
        u16 ob[32];
#pragma unroll
        for (int rr = 0; rr < 4; ++rr)
#pragma unroll
            for (int dd = 0; dd < 8; ++dd)
                ob[rr * 8 + dd] = f2bf(lds[s2 * 4 + rr][c * 9 + 1 + dd]);
        uint4* dst = (uint4*)(Bt + (size_t)(o0 + c) * K_DIM + (size_t)i0 * 8 + s2 * 32);
        const uint4* sp = (const uint4*)ob;
#pragma unroll
        for (int u = 0; u < 4; ++u) dst[u] = sp[u];
    }

    if (t < 32) {
        float sum = 0.f;
#pragma unroll
        for (int rr = 0; rr < 32; ++rr) sum += lds[rr][t * 9];
        atomicAdd(&bias[o0 + t], sum);
    }
}

// ---------------------------------------------------------------------------
// Kernel 2: FUSED basis+GEMM.  C[m][n] = bias[n] + sum_k basisA[m][k]*B[n][k]
// A is never materialized in HBM: each block computes its A-tile from x via
// the Askey-Wilson recurrence during staging (reg-staged swizzled ds_write,
// rule #21-legal), while B stages via gload_lds. r6 free-flow geometry:
// BM=256 x BN=128, BK=64, 512 thr (8 waves 4Mx2N, 64x64/wave, acc 4x4).
// A double-buffer (64 KB) + B double-buffer (32 KB) = 96 KB LDS.
// Per tile: [stageB(t+1); xload(t+2)->reg; fragreads(t); computeA(t+1) from
// x(t+1)-reg (VALU overlaps under MFMA-wait); MFMA(t); __syncthreads()].
// Full drain per tile is ~free: issue-to-drain ~800+ cyc > L2/L3 latency.
// x panel (1 MB/rowBlk) is L2-resident: XCD swizzle groups a rowBlk's 8
// colBlks on one XCD. Verified slot^(r&7) swizzle on both write and read.
// ---------------------------------------------------------------------------
__global__ __launch_bounds__(512) void aw_gemm(
    const float* __restrict__ x,
    const u16* __restrict__ B,
    const float* __restrict__ pa, const float* __restrict__ pb,
    const float* __restrict__ pc, const float* __restrict__ pd,
    const float* __restrict__ pq,
    const float* __restrict__ bias,
    float* __restrict__ C)
{
    __shared__ alignas(16) u16 As[2 * A_TILE];   // 64 KB
    __shared__ alignas(16) u16 Bs[2 * B_TILE];   // 32 KB

    // T1: bijective XCD swizzle; nwg = 256 (32 rowBlks x 8 colBlks)
    int bid = blockIdx.x;
    int logical = (bid & 7) * 32 + (bid >> 3);
    int rowBlk = logical >> 3;
    int colBlk = logical & 7;

    const int tid  = threadIdx.x;
    const int lane = tid & 63;
    const int wid  = tid >> 6;
    const int wr = wid & 3;          // 4 M-waves
    const int wc = wid >> 2;         // 2 N-waves

    // --- Askey-Wilson recurrence constants (per-thread, once) ---
    float a = *pa, bb = *pb, c = *pc, d = *pd, q = *pq;
    float ab = a * bb, cd = c * d, abcd = ab * cd;
    float qp[17];
    qp[0] = 1.f;
#pragma unroll
    for (int k = 1; k <= 16; ++k) qp[k] = qp[k - 1] * q;
    float den1 = 1.f + abcd * q * q;
    float c1x = 2.f * (1.f + ab * q) / den1;
    float c1c = -(a + bb) * (1.f + cd * q) / den1;
    float An_[9], Cn_[9], Sn_[9];
#pragma unroll
    for (int n = 2; n <= 8; ++n) {
        float t1 = 1.f - ab * qp[n - 1];
        float t2 = 1.f - cd * qp[n - 1];
        float t3 = 1.f - abcd * qp[2 * n - 2];
        float t4 = 1.f - abcd * qp[2 * n - 1];
        float t5 = 1.f - abcd * qp[2 * n];
        An_[n] = (t1 * t2 * t3) / (t4 * t5);
        Cn_[n] = ((1.f - qp[n]) * t1 * t2 * t3) / (t3 * t4);
        Sn_[n] = 1.f / (1.f - qp[n]);
    }

    // --- B staging addresses (2 gload_lds per thread; source pre-swizzled) ---
    const u16* gB[2];
    int ldsB[2];
#pragma unroll
    for (int j = 0; j < 2; ++j) {
        int idx = j * 512 + tid;
        int r = idx >> 3, sl = idx & 7;
        gB[j] = B + (size_t)colBlk * BN * K_DIM + (size_t)r * K_DIM + ((sl ^ (r & 7)) << 3);
        ldsB[j] = idx << 3;
    }

    // --- x pointer: thread covers row (tid>>1), i-quad (tid&1) ---
    const float4* xp4 = (const float4*)x
        + (size_t)(rowBlk * BM + (tid >> 1)) * (I_DIM / 4) + (tid & 1);
    const int arow = tid >> 1;
    const int sbase = (tid & 1) * 4;

    // --- fragment byte-offsets (XOR-swizzled reads) ---
    int offA[2][4], offB[2][4];
#pragma unroll
    for (int ks = 0; ks < 2; ++ks) {
#pragma unroll
        for (int mi = 0; mi < 4; ++mi) {
            int r = wr * 64 + mi * 16 + (lane & 15);
            int s = ks * 4 + (lane >> 4);
            offA[ks][mi] = r * 128 + ((s ^ (r & 7)) << 4);
        }
#pragma unroll
        for (int ni = 0; ni < 4; ++ni) {
            int r = wc * 64 + ni * 16 + (lane & 15);
            int s = ks * 4 + (lane >> 4);
            offB[ks][ni] = r * 128 + ((s ^ (r & 7)) << 4);
        }
    }

    f32x4 acc[4][4];
#pragma unroll
    for (int mi = 0; mi < 4; ++mi)
#pragma unroll
        for (int ni = 0; ni < 4; ++ni)
            acc[mi][ni] = (f32x4){0.f, 0.f, 0.f, 0.f};

    auto stageB = [&](int kt, int buf) {
        const int k0 = kt * BK;
        u16* dB = Bs + buf * B_TILE;
        gload_lds16(gB[0] + k0, dB + ldsB[0]);
        gload_lds16(gB[1] + k0, dB + ldsB[1]);
    };

    // compute A-tile rows for tile kt from a float4 of x (4 i's x 8 degrees)
    auto computeA = [&](float4 xv, int ab4) {
        u16* dA = As + ab4 * A_TILE;
        float xs[4] = {xv.x, xv.y, xv.z, xv.w};
#pragma unroll
        for (int j = 0; j < 4; ++j) {
            float xj = xs[j];
            bf16x8 v;
            float p1 = c1x * xj + c1c;
            v[0] = (__bf16)p1;
            float pm2 = 1.f, pm1 = p1;
            float tx = xj + xj;
#pragma unroll
            for (int n = 2; n <= 8; ++n) {
                float pn = ((tx - An_[n]) * pm1 - Cn_[n] * pm2) * Sn_[n];
                v[n - 1] = (__bf16)pn;
                pm2 = pm1; pm1 = pn;
            }
            int sl = sbase + j;
            *(bf16x8*)(dA + arow * 64 + ((sl ^ (arow & 7)) << 3)) = v;
        }
    };

    auto domfma = [&](int buf) {
        const char* aB = (const char*)(As + buf * A_TILE);
        const char* bB = (const char*)(Bs + buf * B_TILE);
        bf16x8 a0[4], b0[4], a1[4], b1[4];
#pragma unroll
        for (int mi = 0; mi < 4; ++mi) a0[mi] = *(const bf16x8*)(aB + offA[0][mi]);
#pragma unroll
        for (int ni = 0; ni < 4; ++ni) b0[ni] = *(const bf16x8*)(bB + offB[0][ni]);
#pragma unroll
        for (int mi = 0; mi < 4; ++mi) a1[mi] = *(const bf16x8*)(aB + offA[1][mi]);
#pragma unroll
        for (int ni = 0; ni < 4; ++ni) b1[ni] = *(const bf16x8*)(bB + offB[1][ni]);
        return (void)0, (void)a0, (void)0;  // placeholder (unused)
    };
    (void)domfma;

    // ---- prologue: stage B(0); compute A(0); prefetch x(1) ----
    stageB(0, 0);
    float4 xP = xp4[0];              // x(0)
    computeA(xP, 0);                 // A(0) -> Abuf0
    float4 xN = xp4[2 + 0 * 0];      // x(1): index kt*2 with kt=1 -> 2
    __syncthreads();                 // drains vmcnt+lgkm; A(0)/B(0) visible

#define ITER(T, XC, XN_)                                                      \
    do {                                                                      \
        const bool doA = (T) + 1 < NT;                                        \
        const bool doX = (T) + 2 < NT;                                        \
        if (doA) stageB((T) + 1, ((T) + 1) & 1);                              \
        if (doX) XN_ = xp4[((T) + 2) * 2];                                    \
        const char* aB = (const char*)(As + ((T) & 1) * A_TILE);              \
        const char* bB = (const char*)(Bs + ((T) & 1) * B_TILE);              \
        bf16x8 a0[4], b0[4], a1[4], b1[4];                                    \
        _Pragma("unroll")                                                     \
        for (int mi = 0; mi < 4; ++mi) a0[mi] = *(const bf16x8*)(aB + offA[0][mi]); \
        _Pragma("unroll")                                                     \
        for (int ni = 0; ni < 4; ++ni) b0[ni] = *(const bf16x8*)(bB + offB[0][ni]); \
        _Pragma("unroll")                                                     \
        for (int mi = 0; mi < 4; ++mi) a1[mi] = *(const bf16x8*)(aB + offA[1][mi]); \
        _Pragma("unroll")                                                     \
        for (int ni = 0; ni < 4; ++ni) b1[ni] = *(const bf16x8*)(bB + offB[1][ni]); \
        if (doA) computeA(XC, ((T) + 1) & 1);                                 \
        __builtin_amdgcn_s_setprio(1);                                        \
        _Pragma("unroll")                                                     \
        for (int mi = 0; mi < 4; ++mi)                                        \
            _Pragma("unroll")                                                 \
            for (int ni = 0; ni < 4; ++ni)                                    \
                acc[mi][ni] = __builtin_amdgcn_mfma_f32_16x16x32_bf16(        \
                    a0[mi], b0[ni], acc[mi][ni], 0, 0, 0);                    \
        _Pragma("unroll")                                                     \
        for (int mi = 0; mi < 4; ++mi)                                        \
            _Pragma("unroll")                                                 \
            for (int ni = 0; ni < 4; ++ni)                                    \
                acc[mi][ni] = __builtin_amdgcn_mfma_f32_16x16x32_bf16(        \
                    a1[mi], b1[ni], acc[mi][ni], 0, 0, 0);                    \
        __builtin_amdgcn_s_setprio(0);                                        \
        if ((T) + 1 < NT) __syncthreads();                                    \
    } while (0)

    for (int t = 0; t < NT; t += 2) {
        ITER(t, xN, xP);
        ITER(t + 1, xP, xN);
    }
#undef ITER

    // epilogue: D layout col=lane&15, row=(lane>>4)*4+j  [m89]
    int gRow = rowBlk * BM + wr * 64;
    int gCol = colBlk * BN + wc * 64;
#pragma unroll
    for (int mi = 0; mi < 4; ++mi) {
#pragma unroll
        for (int ni = 0; ni < 4; ++ni) {
            int rr = gRow + mi * 16 + ((lane >> 4) << 2);
            int cc = gCol + ni * 16 + (lane & 15);
            float bv = bias[cc];
            float* dst = C + (size_t)rr * N_DIM + cc;
#pragma unroll
            for (int j = 0; j < 4; ++j) dst[(size_t)j * N_DIM] = acc[mi][ni][j] + bv;
        }
    }
}

// ---------------------------------------------------------------------------
extern "C" void kernel_launch(void* const* d_in, const int* in_sizes, int n_in,
                              void* d_out, int out_size, void* d_ws, size_t ws_size,
                              hipStream_t stream)
{
    const float* x      = (const float*)d_in[0];
    const float* pa     = (const float*)d_in[1];
    const float* pb     = (const float*)d_in[2];
    const float* pc     = (const float*)d_in[3];
    const float* pd     = (const float*)d_in[4];
    const float* pq     = (const float*)d_in[5];
    const float* coeffs = (const float*)d_in[6];
    float* out = (float*)d_out;

    float* bias = (float*)d_ws;
    const size_t biasBytes = 4096;
    u16* Bt = (u16*)((char*)d_ws + biasBytes);

    hipMemsetAsync(bias, 0, N_DIM * sizeof(float), stream);
    aw_transform<<<1024, 256, 0, stream>>>(coeffs, Bt, bias);
    aw_gemm<<<256, 512, 0, stream>>>(x, Bt, pa, pb, pc, pd, pq, bias, out);
}

// Round 11
// 181.363 us; speedup vs baseline: 1.1866x; 1.1866x over previous
//
#include <hip/hip_runtime.h>
#include <cstdint>

typedef unsigned short u16;
typedef __bf16 bf16x8 __attribute__((ext_vector_type(8)));
typedef float f32x4 __attribute__((ext_vector_type(4)));

#define M_DIM 8192
#define N_DIM 1024
#define I_DIM 1024
#define NDEG 8                    /* stored degrees d=1..8 */
#define K_DIM (I_DIM * NDEG)      /* 8192 */
#define BM 256
#define BN 128
#define BK 64
#define NT (K_DIM / BK)           /* 128 K-tiles */
#define A_TILE (BM * BK)          /* 16384 u16 = 32 KB */
#define B_TILE (BN * BK)          /* 8192  u16 = 16 KB */

__device__ __forceinline__ u16 f2bf(float f) {
    union { float f; uint32_t u; } v; v.f = f;
    return (u16)((v.u + 0x7FFFu + ((v.u >> 16) & 1u)) >> 16);
}

__device__ __forceinline__ void gload_lds16(const u16* g, u16* l) {
    auto lp = reinterpret_cast<__attribute__((address_space(3))) uint32_t*>(
        reinterpret_cast<uintptr_t>(l));
    __builtin_amdgcn_global_load_lds(reinterpret_cast<const uint32_t*>(g), lp, 16, 0, 0);
}

// ---------------------------------------------------------------------------
// device helpers for the fused prep kernel
// ---------------------------------------------------------------------------
__device__ __forceinline__ void do_transform_block(
    int blk, int t, const float* __restrict__ coeffs,
    u16* __restrict__ Bt, float* __restrict__ bias, float (*lds)[292])
{
    int bi = blk >> 5, bo = blk & 31;
    int i0 = bi * 32, o0 = bo * 32;

    {
        int r = t >> 3, s = t & 7;
        const float4* src = (const float4*)(coeffs + ((size_t)(i0 + r) * N_DIM + o0) * 9);
#pragma unroll
        for (int j = 0; j < 9; ++j) {
            float4 v = src[s * 9 + j];
            *(float4*)&lds[r][(s * 9 + j) * 4] = v;
        }
    }
    __syncthreads();

    {
        int c = t >> 3, s2 = t & 7;
        u16 ob[32];
#pragma unroll
        for (int rr = 0; rr < 4; ++rr)
#pragma unroll
            for (int dd = 0; dd < 8; ++dd)
                ob[rr * 8 + dd] = f2bf(lds[s2 * 4 + rr][c * 9 + 1 + dd]);
        uint4* dst = (uint4*)(Bt + (size_t)(o0 + c) * K_DIM + (size_t)i0 * 8 + s2 * 32);
        const uint4* sp = (const uint4*)ob;
#pragma unroll
        for (int u = 0; u < 4; ++u) dst[u] = sp[u];
    }

    if (t < 32) {
        float sum = 0.f;
#pragma unroll
        for (int rr = 0; rr < 32; ++rr) sum += lds[rr][t * 9];
        atomicAdd(&bias[o0 + t], sum);
    }
}

__device__ __forceinline__ void do_basis_thread(
    int gt, const float* __restrict__ x,
    const float* __restrict__ pa, const float* __restrict__ pb,
    const float* __restrict__ pc, const float* __restrict__ pd,
    const float* __restrict__ pq, u16* __restrict__ A, int row0)
{
    int rb = gt >> 7;
    int g  = gt & 127;
    int i0 = g << 3;
    int b  = row0 + rb;

    float a = *pa, bb = *pb, c = *pc, d = *pd, q = *pq;
    float ab = a * bb, cd = c * d, abcd = ab * cd;

    float qp[17];
    qp[0] = 1.f;
#pragma unroll
    for (int k = 1; k <= 16; ++k) qp[k] = qp[k - 1] * q;

    float den1 = 1.f + abcd * q * q;
    float c1x = 2.f * (1.f + ab * q) / den1;
    float c1c = -(a + bb) * (1.f + cd * q) / den1;

    float An[9], Cn[9], Sn[9];
#pragma unroll
    for (int n = 2; n <= 8; ++n) {
        float t1 = 1.f - ab * qp[n - 1];
        float t2 = 1.f - cd * qp[n - 1];
        float t3 = 1.f - abcd * qp[2 * n - 2];
        float t4 = 1.f - abcd * qp[2 * n - 1];
        float t5 = 1.f - abcd * qp[2 * n];
        An[n] = (t1 * t2 * t3) / (t4 * t5);
        Cn[n] = ((1.f - qp[n]) * t1 * t2 * t3) / (t3 * t4);
        Sn[n] = 1.f / (1.f - qp[n]);
    }

    const float4* x4 = (const float4*)(x + (size_t)b * I_DIM + i0);
    float4 v0 = x4[0], v1 = x4[1];
    float xv[8] = {v0.x, v0.y, v0.z, v0.w, v1.x, v1.y, v1.z, v1.w};

    u16 ob[64];
#pragma unroll
    for (int j = 0; j < 8; ++j) {
        float xj = xv[j];
        float p1 = c1x * xj + c1c;
        ob[j * 8 + 0] = f2bf(p1);
        float pm2 = 1.f, pm1 = p1;
#pragma unroll
        for (int n = 2; n <= 8; ++n) {
            float pn = ((2.f * xj - An[n]) * pm1 - Cn[n] * pm2) * Sn[n];
            ob[j * 8 + n - 1] = f2bf(pn);
            pm2 = pm1; pm1 = pn;
        }
    }

    uint4* dst = (uint4*)(A + (size_t)rb * K_DIM + (size_t)i0 * 8);
    const uint4* s = (const uint4*)ob;
#pragma unroll
    for (int u = 0; u < 8; ++u) dst[u] = s[u];
}

// ---------------------------------------------------------------------------
// Kernel 1 (fused prep): blocks [0,1024) do the coeffs transform; blocks
// [1024, 1024+4096) do the basis for all 8192 rows. Both are memory-bound
// and independent -> overlapping them streams ~222 MB in one dispatch.
// ---------------------------------------------------------------------------
__global__ __launch_bounds__(256) void aw_prep(
    const float* __restrict__ coeffs, const float* __restrict__ x,
    const float* __restrict__ pa, const float* __restrict__ pb,
    const float* __restrict__ pc, const float* __restrict__ pd,
    const float* __restrict__ pq,
    u16* __restrict__ Bt, float* __restrict__ bias, u16* __restrict__ A)
{
    __shared__ float lds[32][292];
    int blk = blockIdx.x;
    int t = threadIdx.x;
    if (blk < 1024) {
        do_transform_block(blk, t, coeffs, Bt, bias, lds);
    } else {
        int gt = (blk - 1024) * 256 + t;
        do_basis_thread(gt, x, pa, pb, pc, pd, pq, A, 0);
    }
}

// standalone versions (fallback chunked path)
__global__ __launch_bounds__(256) void aw_transform(
    const float* __restrict__ coeffs, u16* __restrict__ Bt, float* __restrict__ bias)
{
    __shared__ float lds[32][292];
    do_transform_block(blockIdx.x, threadIdx.x, coeffs, Bt, bias, lds);
}

__global__ void aw_basis(const float* __restrict__ x,
                         const float* __restrict__ pa, const float* __restrict__ pb,
                         const float* __restrict__ pc, const float* __restrict__ pd,
                         const float* __restrict__ pq,
                         u16* __restrict__ A, int row0)
{
    do_basis_thread(blockIdx.x * 256 + threadIdx.x, x, pa, pb, pc, pd, pq, A, row0);
}

// ---------------------------------------------------------------------------
// Kernel 2: K-paired free-flow GEMM (r8, best measured: 129.1 us, 46.6% MFMA).
// BM=256 x BN=128, BK=64, 512 thr = 8 waves: 4 quadrant-owners (2M x 2N,
// 128x64/wave = 8x4 frags) x 2 K-halves. Triple-buffered LDS (144 KiB);
// free-flow interior, ONE counted vmcnt(6) + ONE barrier per K-tile.
// Verified slot^(r&7) swizzle (0 conflicts). K-half partials merged via LDS.
// T1 XCD swizzle, T5 setprio.
// ---------------------------------------------------------------------------
__global__ __launch_bounds__(512) void aw_gemm(
    const u16* __restrict__ A,
    const u16* __restrict__ B,
    const float* __restrict__ bias,
    float* __restrict__ C,
    int row0, int rowBlocks)
{
    __shared__ alignas(16) u16 smem[3 * A_TILE + 3 * B_TILE];   // 144 KB
    u16* As = smem;
    u16* Bs = smem + 3 * A_TILE;

    int nwg = rowBlocks * 8;
    int bid = blockIdx.x;
    int per = nwg >> 3;
    int logical = (bid & 7) * per + (bid >> 3);
    int rowBlk = logical >> 3;       // 8 col-blocks
    int colBlk = logical & 7;

    const int tid  = threadIdx.x;
    const int lane = tid & 63;
    const int wid  = tid >> 6;
    const int quad = wid & 3;        // 4 C-quadrants (2M x 2N)
    const int wr   = quad >> 1;      // 0..1 (128-row half)
    const int wc   = quad & 1;       // 0..1 (64-col half)
    const int myKs = wid >> 2;       // 0..1 (32-wide K half of each tile)

    // --- staging addresses (k0 added per tile); source slot pre-swizzled ---
    const u16* gA[4]; const u16* gB[2];
    int ldsA[4], ldsB[2];
#pragma unroll
    for (int j = 0; j < 4; ++j) {
        int idx = j * 512 + tid;
        int r = idx >> 3, sl = idx & 7;
        gA[j] = A + (size_t)rowBlk * BM * K_DIM + (size_t)r * K_DIM + ((sl ^ (r & 7)) << 3);
        ldsA[j] = idx << 3;
    }
#pragma unroll
    for (int j = 0; j < 2; ++j) {
        int idx = j * 512 + tid;
        int r = idx >> 3, sl = idx & 7;
        gB[j] = B + (size_t)colBlk * BN * K_DIM + (size_t)r * K_DIM + ((sl ^ (r & 7)) << 3);
        ldsB[j] = idx << 3;
    }

    // --- fragment byte-offsets for this wave's ks-half (swizzled reads) ---
    int offA[8], offB[4];
#pragma unroll
    for (int mi = 0; mi < 8; ++mi) {
        int r = wr * 128 + mi * 16 + (lane & 15);
        int s = myKs * 4 + (lane >> 4);
        offA[mi] = r * 128 + ((s ^ (r & 7)) << 4);
    }
#pragma unroll
    for (int ni = 0; ni < 4; ++ni) {
        int r = wc * 64 + ni * 16 + (lane & 15);
        int s = myKs * 4 + (lane >> 4);
        offB[ni] = r * 128 + ((s ^ (r & 7)) << 4);
    }

    f32x4 acc[8][4];
#pragma unroll
    for (int mi = 0; mi < 8; ++mi)
#pragma unroll
        for (int ni = 0; ni < 4; ++ni)
            acc[mi][ni] = (f32x4){0.f, 0.f, 0.f, 0.f};

    auto stage = [&](int kt, int buf) {
        const int k0 = kt * BK;
        u16* dA = As + buf * A_TILE;
        u16* dB = Bs + buf * B_TILE;
        gload_lds16(gA[0] + k0, dA + ldsA[0]);
        gload_lds16(gA[1] + k0, dA + ldsA[1]);
        gload_lds16(gA[2] + k0, dA + ldsA[2]);
        gload_lds16(gA[3] + k0, dA + ldsA[3]);
        gload_lds16(gB[0] + k0, dB + ldsB[0]);
        gload_lds16(gB[1] + k0, dB + ldsB[1]);
    };

    // prologue: 2 tiles in flight (12 loads), wait for tile 0
    stage(0, 0);
    stage(1, 1);
    asm volatile("s_waitcnt vmcnt(6)" ::: "memory");
    __builtin_amdgcn_s_barrier();

    int buf = 0;
    for (int t = 0; t < NT; ++t) {
        const char* aB = (const char*)(As + buf * A_TILE);
        const char* bB = (const char*)(Bs + buf * B_TILE);
        int nb = buf + 2; if (nb >= 3) nb -= 3;
        const bool pf = (t + 2 < NT);

        // fragment reads for this wave's ks-half; prefetch issue interleaved.
        bf16x8 fa[8], fb[4];
#pragma unroll
        for (int mi = 0; mi < 4; ++mi) fa[mi] = *(const bf16x8*)(aB + offA[mi]);
#pragma unroll
        for (int ni = 0; ni < 2; ++ni) fb[ni] = *(const bf16x8*)(bB + offB[ni]);
        if (pf) stage(t + 2, nb);
#pragma unroll
        for (int mi = 4; mi < 8; ++mi) fa[mi] = *(const bf16x8*)(aB + offA[mi]);
#pragma unroll
        for (int ni = 2; ni < 4; ++ni) fb[ni] = *(const bf16x8*)(bB + offB[ni]);

        __builtin_amdgcn_s_setprio(1);
#pragma unroll
        for (int mi = 0; mi < 8; ++mi)
#pragma unroll
            for (int ni = 0; ni < 4; ++ni)
                acc[mi][ni] = __builtin_amdgcn_mfma_f32_16x16x32_bf16(
                    fa[mi], fb[ni], acc[mi][ni], 0, 0, 0);
        __builtin_amdgcn_s_setprio(0);

        // single counted drain + single barrier per K-tile
        if (pf)              { asm volatile("s_waitcnt vmcnt(6)" ::: "memory"); }
        else if (t + 1 < NT) { asm volatile("s_waitcnt vmcnt(0)" ::: "memory"); }
        __builtin_amdgcn_s_barrier();

        buf += 1; if (buf >= 3) buf -= 3;
    }

    // ---- epilogue: merge K-half partials via LDS (128 KB of the 144) ----
    float* red = (float*)smem;
    if (myKs == 1) {
        f32x4* dst = (f32x4*)red + quad * 2048;   // 32 KB per quadrant
#pragma unroll
        for (int mi = 0; mi < 8; ++mi)
#pragma unroll
            for (int ni = 0; ni < 4; ++ni)
                dst[(mi * 4 + ni) * 64 + lane] = acc[mi][ni];
    }
    __syncthreads();
    if (myKs == 0) {
        const f32x4* src = (const f32x4*)red + quad * 2048;
#pragma unroll
        for (int mi = 0; mi < 8; ++mi)
#pragma unroll
            for (int ni = 0; ni < 4; ++ni) {
                f32x4 p = src[(mi * 4 + ni) * 64 + lane];
                acc[mi][ni] += p;
            }

        // D layout col=lane&15, row=(lane>>4)*4+j  [m89]
        int gRow = row0 + rowBlk * BM + wr * 128;
        int gCol = colBlk * BN + wc * 64;
#pragma unroll
        for (int mi = 0; mi < 8; ++mi) {
#pragma unroll
            for (int ni = 0; ni < 4; ++ni) {
                int rr = gRow + mi * 16 + ((lane >> 4) << 2);
                int cc = gCol + ni * 16 + (lane & 15);
                float bv = bias[cc];
                float* dst = C + (size_t)rr * N_DIM + cc;
#pragma unroll
                for (int j = 0; j < 4; ++j) dst[(size_t)j * N_DIM] = acc[mi][ni][j] + bv;
            }
        }
    }
}

// ---------------------------------------------------------------------------
extern "C" void kernel_launch(void* const* d_in, const int* in_sizes, int n_in,
                              void* d_out, int out_size, void* d_ws, size_t ws_size,
                              hipStream_t stream)
{
    const float* x      = (const float*)d_in[0];
    const float* pa     = (const float*)d_in[1];
    const float* pb     = (const float*)d_in[2];
    const float* pc     = (const float*)d_in[3];
    const float* pd     = (const float*)d_in[4];
    const float* pq     = (const float*)d_in[5];
    const float* coeffs = (const float*)d_in[6];
    float* out = (float*)d_out;

    float* bias = (float*)d_ws;
    const size_t biasBytes = 4096;
    u16* Bt = (u16*)((char*)d_ws + biasBytes);
    const size_t btBytes = (size_t)N_DIM * K_DIM * sizeof(u16);   // 16.8 MB
    u16* Abuf = (u16*)((char*)d_ws + biasBytes + btBytes);
    size_t used = biasBytes + btBytes;
    size_t avail = ws_size > used ? ws_size - used : 0;
    const size_t aFullBytes = (size_t)M_DIM * K_DIM * sizeof(u16);  // 134 MB

    hipMemsetAsync(bias, 0, N_DIM * sizeof(float), stream);

    if (avail >= aFullBytes) {
        // fused prep: transform (1024 blocks) + full-M basis (4096 blocks)
        aw_prep<<<1024 + (M_DIM * 128) / 256, 256, 0, stream>>>(
            coeffs, x, pa, pb, pc, pd, pq, Bt, bias, Abuf);
        aw_gemm<<<(M_DIM / BM) * 8, 512, 0, stream>>>(Abuf, Bt, bias, out, 0, M_DIM / BM);
    } else {
        int chunk = M_DIM;
        while (chunk > 256 && (size_t)chunk * K_DIM * sizeof(u16) > avail) chunk >>= 1;
        aw_transform<<<1024, 256, 0, stream>>>(coeffs, Bt, bias);
        for (int row0 = 0; row0 < M_DIM; row0 += chunk) {
            aw_basis<<<(chunk * 128) / 256, 256, 0, stream>>>(x, pa, pb, pc, pd, pq, Abuf, row0);
            aw_gemm<<<(chunk / BM) * 8, 512, 0, stream>>>(Abuf, Bt, bias, out, row0, chunk / BM);
        }
    }
}